// Round 18
// baseline (93.904 us; speedup 1.0000x reference)
//
#include <hip/hip_runtime.h>
#include <hip/hip_bf16.h>
#include <math.h>

#define NQ 50000
#define NS 50000
#define KK 32
#define CF 64      // feat channels
#define CW 67      // conv input channels (3 + 64)
#define CO 64      // output channels
#define WAVES 4
#define NPAIR (NQ / 2)        // 25000 query pairs
#define GGRID 2048            // 8 blocks/CU; halves split by blockIdx&7 (XCD)
#define GPB (GGRID / 2)       // 1024 blocks per channel-half group
#define GRIDFB 1024           // fallback grid
#define GSFB (GRIDFB * WAVES)
#define PTILES ((NS + 1 + KK - 1) / KK)   // 1563 support tiles (incl. pad row)
#define HHALF 800016          // floats per half-table: (NS+1)*32 ushort / 2

typedef __attribute__((ext_vector_type(8))) short bf16x8;
typedef __attribute__((ext_vector_type(16))) float f32x16;

__device__ inline short f2b(float x) {
    union { __hip_bfloat16 b; short s; } u;
    u.b = __float2bfloat16(x);   // RNE
    return u.s;
}

__device__ inline bf16x8 pack2(const float4 a, const float4 b) {
    bf16x8 r;
    r[0] = f2b(a.x); r[1] = f2b(a.y); r[2] = f2b(a.z); r[3] = f2b(a.w);
    r[4] = f2b(b.x); r[5] = f2b(b.y); r[6] = f2b(b.z); r[7] = f2b(b.w);
    return r;
}

__device__ inline bf16x8 zero8() {
    bf16x8 r;
#pragma unroll
    for (int j = 0; j < 8; ++j) r[j] = 0;
    return r;
}

// B fragments: cols = output channels, k0..63 = Wf (w[o][3..66]), k64..66 = Wc.
__device__ inline void build_bfrag(const float* __restrict__ w, int col, int half,
                                   bf16x8 bfrag[5][2]) {
#pragma unroll
    for (int c = 0; c < 5; ++c) {
#pragma unroll
        for (int t = 0; t < 2; ++t) {
            const int o = t * 32 + col;
            bf16x8 r;
#pragma unroll
            for (int j = 0; j < 8; ++j) {
                const int k = c * 16 + half * 8 + j;
                float v = 0.f;
                if (k < 64)      v = w[o * CW + 3 + k];
                else if (k < 67) v = w[o * CW + (k - 64)];
                r[j] = f2b(v);
            }
            bfrag[c][t] = r;
        }
    }
}

// Prep: H[r][o] = feat[r]·Wf[o] + sp[r]·Wc[o]; row NS = zeros.
// Output split by channel half: H0[r][0..31], H1[r][0..31] (64B rows).
__global__ __launch_bounds__(256, 3) void gc_prep(
    const float* __restrict__ sp,
    const float* __restrict__ feat,
    const float* __restrict__ w,
    unsigned short* __restrict__ H0,   // [NS+1][32] ch 0-31
    unsigned short* __restrict__ H1)   // [NS+1][32] ch 32-63
{
    const int tid  = threadIdx.x;
    const int lane = tid & 63;
    const int wv   = tid >> 6;
    const int col  = lane & 31;
    const int half = lane >> 5;

    const int tile = blockIdx.x * WAVES + wv;
    if (tile >= PTILES) return;
    const int base = tile * 32;
    const int r    = base + col;

    bf16x8 bfrag[5][2];
    build_bfrag(w, col, half, bfrag);

    bf16x8 A0, A1, A2, A3, a4;
    if (r < NS) {
        const float4* fp = (const float4*)(feat + (size_t)r * CF);
        A0 = pack2(fp[half * 2],      fp[half * 2 + 1]);
        A1 = pack2(fp[4 + half * 2],  fp[4 + half * 2 + 1]);
        A2 = pack2(fp[8 + half * 2],  fp[8 + half * 2 + 1]);
        A3 = pack2(fp[12 + half * 2], fp[12 + half * 2 + 1]);
        a4 = zero8();
        if (half == 0) {
            a4[0] = f2b(sp[r * 3 + 0]);
            a4[1] = f2b(sp[r * 3 + 1]);
            a4[2] = f2b(sp[r * 3 + 2]);
        }
    } else {
        A0 = zero8(); A1 = zero8(); A2 = zero8(); A3 = zero8(); a4 = zero8();
    }

    f32x16 acc0, acc1;
#pragma unroll
    for (int g = 0; g < 16; ++g) { acc0[g] = 0.f; acc1[g] = 0.f; }
    acc0 = __builtin_amdgcn_mfma_f32_32x32x16_bf16(A0, bfrag[0][0], acc0, 0, 0, 0);
    acc1 = __builtin_amdgcn_mfma_f32_32x32x16_bf16(A0, bfrag[0][1], acc1, 0, 0, 0);
    acc0 = __builtin_amdgcn_mfma_f32_32x32x16_bf16(A1, bfrag[1][0], acc0, 0, 0, 0);
    acc1 = __builtin_amdgcn_mfma_f32_32x32x16_bf16(A1, bfrag[1][1], acc1, 0, 0, 0);
    acc0 = __builtin_amdgcn_mfma_f32_32x32x16_bf16(A2, bfrag[2][0], acc0, 0, 0, 0);
    acc1 = __builtin_amdgcn_mfma_f32_32x32x16_bf16(A2, bfrag[2][1], acc1, 0, 0, 0);
    acc0 = __builtin_amdgcn_mfma_f32_32x32x16_bf16(A3, bfrag[3][0], acc0, 0, 0, 0);
    acc1 = __builtin_amdgcn_mfma_f32_32x32x16_bf16(A3, bfrag[3][1], acc1, 0, 0, 0);
    acc0 = __builtin_amdgcn_mfma_f32_32x32x16_bf16(a4, bfrag[4][0], acc0, 0, 0, 0);
    acc1 = __builtin_amdgcn_mfma_f32_32x32x16_bf16(a4, bfrag[4][1], acc1, 0, 0, 0);

    // C layout (verified m74/m101): col = lane&31, row = (g&3)+8*(g>>2)+4*(lane>>5)
#pragma unroll
    for (int g = 0; g < 16; ++g) {
        const int row = (g & 3) + 8 * (g >> 2) + 4 * half;
        const int rr  = base + row;
        if (rr <= NS) {
            H0[(size_t)rr * 32 + col] = (unsigned short)f2b(acc0[g]);
            H1[(size_t)rr * 32 + col] = (unsigned short)f2b(acc1[g]);
        }
    }
}

// Gather: XCD-pinned channel halves (R17, proven FETCH 56->25MB) with
// R15-style lean addressing: readlane (SALU) index pair + one cndmask +
// one lshl_add -> saddr/voffset ushort load. Pad census hoisted via ballot.
template <bool MIN>
__global__ __launch_bounds__(256, 3) void gc_gather(
    const float* __restrict__ qp,
    const unsigned short* __restrict__ H0,
    const unsigned short* __restrict__ H1,
    const float* __restrict__ w,
    const int*   __restrict__ inds,
    float* __restrict__ zmax,                // d_out [NQ][64]
    float* __restrict__ zmin,                // ws (optional)
    float* __restrict__ partials)            // [GGRID][64]
{
    __shared__ float red[WAVES][64];

    const int tid  = threadIdx.x;
    const int lane = tid & 63;
    const int wv   = tid >> 6;
    const int ch   = lane & 31;
    const int half = lane >> 5;

    const int j     = blockIdx.x & 7;
    const int group = (j < 4) ? 0 : 1;                  // XCD-pinned half
    const int gblk  = (blockIdx.x >> 3) * 4 + (j & 3);  // [0, GPB)
    const int chOff = group * 32;
    const unsigned short* __restrict__ Hg = group ? H1 : H0;

    const float Wc0 = w[(chOff + ch) * CW + 0];
    const float Wc1 = w[(chOff + ch) * CW + 1];
    const float Wc2 = w[(chOff + ch) * CW + 2];

    float csum = 0.f, csq = 0.f;

    for (int p = gblk * WAVES + wv; p < NPAIR; p += GPB * WAVES) {
        const int q = 2 * p + half;
        const int vii = inds[q * KK + ch];      // 256B coalesced per wave
        const float qx = qp[q * 3 + 0];
        const float qy = qp[q * 3 + 1];
        const float qz = qp[q * 3 + 2];
        const float qwc = qx * Wc0 + qy * Wc1 + qz * Wc2;

        // pad census once per pair (pad index == NS)
        const unsigned long long pm = __ballot(vii >= NS);
        const int padc = half ? __popcll(pm >> 32)
                              : __popcll(pm & 0xFFFFFFFFull);
        const float nv = (float)(KK - padc);
        const bool haspad = (padc != 0);

        float hs = 0.f, hsq = 0.f, hmx = -1e38f, hmn = 1e38f;
#pragma unroll
        for (int n = 0; n < KK; ++n) {
            const int iA = __builtin_amdgcn_readlane(vii, n);        // SALU
            const int iB = __builtin_amdgcn_readlane(vii, n + 32);   // SALU
            const int idx = half ? iB : iA;          // 1 cndmask (cmp hoisted)
            const unsigned off = (unsigned)(idx * 32 + ch);
            const unsigned int hb = Hg[off];         // saddr + 32b voffset
            union { unsigned u; float f; } cv; cv.u = hb << 16;
            hs += cv.f;                              // pad row: H=0, adds 0
            hsq = fmaf(cv.f, cv.f, hsq);
            hmx = fmaxf(hmx, (idx < NS) ? cv.f : -1e38f);
            if (MIN) hmn = fminf(hmn, (idx < NS) ? cv.f : 1e38f);
        }
        float maxz = hmx - qwc;                      // z_valid = H - q·Wc
        if (haspad) maxz = fmaxf(maxz, 0.f);         // pad z = 0 exactly
        zmax[q * CO + chOff + ch] = maxz;
        if (MIN) {
            float minz = hmn - qwc;
            if (haspad) minz = fminf(minz, 0.f);
            zmin[q * CO + chOff + ch] = minz;
        }
        csum += hs - nv * qwc;
        csq  += hsq - 2.f * qwc * hs + nv * qwc * qwc;
    }

    // lanes ch and ch+32 hold same channel (different queries) -> combine
    csum += __shfl_xor(csum, 32);
    csq  += __shfl_xor(csq, 32);
    if (lane < 32) red[wv][ch] = csum;
    __syncthreads();
    if (tid < 32) {
        partials[blockIdx.x * 64 + tid] =
            red[0][tid] + red[1][tid] + red[2][tid] + red[3][tid];
    }
    __syncthreads();
    if (lane < 32) red[wv][ch] = csq;
    __syncthreads();
    if (tid < 32) {
        partials[blockIdx.x * 64 + 32 + tid] =
            red[0][tid] + red[1][tid] + red[2][tid] + red[3][tid];
    }
}

// Fallback (ws too small — not expected): R4-style direct gather + MFMA.
__global__ __launch_bounds__(256, 3) void gc_fb(
    const float* __restrict__ qp,
    const float* __restrict__ sp,
    const float* __restrict__ feat,
    const float* __restrict__ w,
    const int*   __restrict__ inds,
    float* __restrict__ zmax,
    float* __restrict__ partials)   // [GRIDFB][128]
{
    __shared__ float red[WAVES][128];
    const int tid  = threadIdx.x;
    const int lane = tid & 63;
    const int wv   = tid >> 6;
    const int col  = lane & 31;
    const int half = lane >> 5;

    bf16x8 bfrag[5][2];
    build_bfrag(w, col, half, bfrag);

    float csum0 = 0.f, csum1 = 0.f, csq0 = 0.f, csq1 = 0.f;

    for (int qb = blockIdx.x * WAVES; qb < NQ; qb += GSFB) {
        const int q = qb + wv;
        const int ii = inds[q * KK + col];
        const bool val = (ii < NS);
        bf16x8 A0, A1, A2, A3, a4;
        if (val) {
            const float4* fp = (const float4*)(feat + (size_t)ii * CF);
            A0 = pack2(fp[half * 2],      fp[half * 2 + 1]);
            A1 = pack2(fp[4 + half * 2],  fp[4 + half * 2 + 1]);
            A2 = pack2(fp[8 + half * 2],  fp[8 + half * 2 + 1]);
            A3 = pack2(fp[12 + half * 2], fp[12 + half * 2 + 1]);
            a4 = zero8();
            if (half == 0) {
                a4[0] = f2b(sp[ii * 3 + 0] - qp[q * 3 + 0]);
                a4[1] = f2b(sp[ii * 3 + 1] - qp[q * 3 + 1]);
                a4[2] = f2b(sp[ii * 3 + 2] - qp[q * 3 + 2]);
            }
        } else {
            A0 = zero8(); A1 = zero8(); A2 = zero8(); A3 = zero8(); a4 = zero8();
        }

        f32x16 acc0, acc1;
#pragma unroll
        for (int g = 0; g < 16; ++g) { acc0[g] = 0.f; acc1[g] = 0.f; }
        acc0 = __builtin_amdgcn_mfma_f32_32x32x16_bf16(A0, bfrag[0][0], acc0, 0, 0, 0);
        acc1 = __builtin_amdgcn_mfma_f32_32x32x16_bf16(A0, bfrag[0][1], acc1, 0, 0, 0);
        acc0 = __builtin_amdgcn_mfma_f32_32x32x16_bf16(A1, bfrag[1][0], acc0, 0, 0, 0);
        acc1 = __builtin_amdgcn_mfma_f32_32x32x16_bf16(A1, bfrag[1][1], acc1, 0, 0, 0);
        acc0 = __builtin_amdgcn_mfma_f32_32x32x16_bf16(A2, bfrag[2][0], acc0, 0, 0, 0);
        acc1 = __builtin_amdgcn_mfma_f32_32x32x16_bf16(A2, bfrag[2][1], acc1, 0, 0, 0);
        acc0 = __builtin_amdgcn_mfma_f32_32x32x16_bf16(A3, bfrag[3][0], acc0, 0, 0, 0);
        acc1 = __builtin_amdgcn_mfma_f32_32x32x16_bf16(A3, bfrag[3][1], acc1, 0, 0, 0);
        acc0 = __builtin_amdgcn_mfma_f32_32x32x16_bf16(a4, bfrag[4][0], acc0, 0, 0, 0);
        acc1 = __builtin_amdgcn_mfma_f32_32x32x16_bf16(a4, bfrag[4][1], acc1, 0, 0, 0);

        float m0 = acc0[0], m1 = acc1[0];
        float s0 = 0.f, s1 = 0.f, q0 = 0.f, q1 = 0.f;
#pragma unroll
        for (int g = 0; g < 16; ++g) {
            m0 = fmaxf(m0, acc0[g]); m1 = fmaxf(m1, acc1[g]);
            s0 += acc0[g]; s1 += acc1[g];
            q0 = fmaf(acc0[g], acc0[g], q0); q1 = fmaf(acc1[g], acc1[g], q1);
        }
        csum0 += s0; csum1 += s1; csq0 += q0; csq1 += q1;
        m0 = fmaxf(m0, __shfl_xor(m0, 32));
        m1 = fmaxf(m1, __shfl_xor(m1, 32));
        zmax[q * CO + half * 32 + col] = half ? m1 : m0;
    }

    csum0 += __shfl_xor(csum0, 32);
    csum1 += __shfl_xor(csum1, 32);
    csq0  += __shfl_xor(csq0, 32);
    csq1  += __shfl_xor(csq1, 32);
    if (lane < 32) {
        red[wv][col]      = csum0;
        red[wv][32 + col] = csum1;
        red[wv][64 + col] = csq0;
        red[wv][96 + col] = csq1;
    }
    __syncthreads();
    if (tid < 128) {
        partials[blockIdx.x * 128 + tid] =
            red[0][tid] + red[1][tid] + red[2][tid] + red[3][tid];
    }
}

// finalize for split layout: par[b][0..31]=sum, [32..63]=sumsq of block's half.
__global__ void gc_finalize2(const float* __restrict__ partials,
                             const float* __restrict__ gamma,
                             const float* __restrict__ beta,
                             float* __restrict__ sb)
{
    __shared__ double rs[256], rq[256];
    const int o = blockIdx.x;       // channel 0..63
    const int t = threadIdx.x;
    const int myg = o >> 5;
    const int och = o & 31;
    double s = 0.0, qq = 0.0;
    for (int b = t; b < GGRID; b += 256) {
        const int grp = ((b & 7) < 4) ? 0 : 1;
        if (grp == myg) {
            s  += (double)partials[b * 64 + och];
            qq += (double)partials[b * 64 + 32 + och];
        }
    }
    rs[t] = s; rq[t] = qq;
    __syncthreads();
    for (int w2 = 128; w2 > 0; w2 >>= 1) {
        if (t < w2) { rs[t] += rs[t + w2]; rq[t] += rq[t + w2]; }
        __syncthreads();
    }
    if (t == 0) {
        const double n = (double)NQ * (double)KK;
        const double mean = rs[0] / n;
        const double var  = rq[0] / n - mean * mean;
        const float sc = gamma[o] * (float)(1.0 / sqrt(var + 1e-5));
        const float bi = beta[o] - (float)mean * sc;
        sb[o]      = sc;
        sb[64 + o] = bi;
    }
}

// finalize for fallback layout (128-stride partials).
__global__ void gc_finalize(const float* __restrict__ partials, int nblk,
                            const float* __restrict__ gamma,
                            const float* __restrict__ beta,
                            float* __restrict__ sb)
{
    __shared__ double rs[256], rq[256];
    const int o = blockIdx.x;
    const int t = threadIdx.x;
    double s = 0.0, qq = 0.0;
    for (int b = t; b < nblk; b += 256) {
        s  += (double)partials[b * 128 + o];
        qq += (double)partials[b * 128 + 64 + o];
    }
    rs[t] = s; rq[t] = qq;
    __syncthreads();
    for (int w2 = 128; w2 > 0; w2 >>= 1) {
        if (t < w2) { rs[t] += rs[t + w2]; rq[t] += rq[t + w2]; }
        __syncthreads();
    }
    if (t == 0) {
        const double n = (double)NQ * (double)KK;
        const double mean = rs[0] / n;
        const double var  = rq[0] / n - mean * mean;
        const float sc = gamma[o] * (float)(1.0 / sqrt(var + 1e-5));
        const float bi = beta[o] - (float)mean * sc;
        sb[o]      = sc;
        sb[64 + o] = bi;
    }
}

// out = leaky(scale * z + bias), in place on d_out (float4-wide).
__global__ void gc_bnact(float4* __restrict__ out,
                         const float4* __restrict__ zmin,
                         const float* __restrict__ sb,
                         int has_min)
{
    const int i  = blockIdx.x * 256 + threadIdx.x;   // < NQ*CO/4
    const int ob = (i & 15) * 4;
    const float4 s4 = *(const float4*)(sb + ob);
    const float4 b4 = *(const float4*)(sb + 64 + ob);
    float4 z4 = out[i];
    if (has_min && (s4.x < 0.f || s4.y < 0.f || s4.z < 0.f || s4.w < 0.f)) {
        const float4 n4 = zmin[i];
        if (s4.x < 0.f) z4.x = n4.x;
        if (s4.y < 0.f) z4.y = n4.y;
        if (s4.z < 0.f) z4.z = n4.z;
        if (s4.w < 0.f) z4.w = n4.w;
    }
    float4 v;
    v.x = s4.x * z4.x + b4.x;
    v.y = s4.y * z4.y + b4.y;
    v.z = s4.z * z4.z + b4.z;
    v.w = s4.w * z4.w + b4.w;
    v.x = (v.x >= 0.f) ? v.x : 0.1f * v.x;
    v.y = (v.y >= 0.f) ? v.y : 0.1f * v.y;
    v.z = (v.z >= 0.f) ? v.z : 0.1f * v.z;
    v.w = (v.w >= 0.f) ? v.w : 0.1f * v.w;
    out[i] = v;
}

extern "C" void kernel_launch(void* const* d_in, const int* in_sizes, int n_in,
                              void* d_out, int out_size, void* d_ws, size_t ws_size,
                              hipStream_t stream) {
    const float* q_points = (const float*)d_in[0];
    const float* s_points = (const float*)d_in[1];
    const float* feat     = (const float*)d_in[2];
    const float* conv_w   = (const float*)d_in[3];
    const float* gamma    = (const float*)d_in[4];
    const float* beta     = (const float*)d_in[5];
    const int*   inds     = (const int*)d_in[6];

    float* ws  = (float*)d_ws;
    float* sb  = ws;                               // 128 floats
    float* par = ws + 128;                         // GGRID*64 floats (131072)
    float* H0f = par + GGRID * 64;                 // HHALF floats each half-table
    float* H1f = H0f + HHALF;
    float* zmn = H1f + HHALF;                      // NQ*CO floats (optional)

    const size_t need_tab = (size_t)(128 + GGRID * 64 + 2 * HHALF) * 4;   // ~6.9MB
    const size_t need_min = need_tab + (size_t)NQ * CO * 4;               // ~19.7MB
    const bool has_tab = ws_size >= need_tab;
    const bool has_min = ws_size >= need_min;

    float* zmax = (float*)d_out;
    unsigned short* H0 = (unsigned short*)H0f;
    unsigned short* H1 = (unsigned short*)H1f;

    if (has_tab) {
        gc_prep<<<(PTILES + WAVES - 1) / WAVES, 256, 0, stream>>>(
            s_points, feat, conv_w, H0, H1);
        if (has_min) {
            gc_gather<true><<<GGRID, 256, 0, stream>>>(
                q_points, H0, H1, conv_w, inds, zmax, zmn, par);
        } else {
            gc_gather<false><<<GGRID, 256, 0, stream>>>(
                q_points, H0, H1, conv_w, inds, zmax, nullptr, par);
        }
        gc_finalize2<<<64, 256, 0, stream>>>(par, gamma, beta, sb);
    } else {
        gc_fb<<<GRIDFB, 256, 0, stream>>>(
            q_points, s_points, feat, conv_w, inds, zmax, par);
        gc_finalize<<<64, 256, 0, stream>>>(par, GRIDFB, gamma, beta, sb);
    }
    gc_bnact<<<(NQ * CO / 4 + 255) / 256, 256, 0, stream>>>(
        (float4*)d_out, (const float4*)zmn, sb, (has_min && has_tab) ? 1 : 0);
}

// Round 19
// 52.381 us; speedup vs baseline: 1.7927x; 1.7927x over previous
//
#include <hip/hip_runtime.h>
#include <hip/hip_bf16.h>
#include <math.h>

#define NQ 50000
#define NS 50000
#define KK 32
#define CF 64      // feat channels
#define CW 67      // conv input channels (3 + 64)
#define CO 64      // output channels
#define WAVES 4
#define GRIDG 2048            // gather grid: 8 blocks/CU
#define GRIDFB 1024           // fallback grid
#define GSFB (GRIDFB * WAVES)
#define PTILES ((NS + 1 + KK - 1) / KK)   // 1563 support tiles (incl. pad row)
#define HFULL 1600032         // floats: (NS+1)*64 ushort

typedef __attribute__((ext_vector_type(8))) short bf16x8;
typedef __attribute__((ext_vector_type(16))) float f32x16;

__device__ inline short f2b(float x) {
    union { __hip_bfloat16 b; short s; } u;
    u.b = __float2bfloat16(x);   // RNE
    return u.s;
}

__device__ inline bf16x8 pack2(const float4 a, const float4 b) {
    bf16x8 r;
    r[0] = f2b(a.x); r[1] = f2b(a.y); r[2] = f2b(a.z); r[3] = f2b(a.w);
    r[4] = f2b(b.x); r[5] = f2b(b.y); r[6] = f2b(b.z); r[7] = f2b(b.w);
    return r;
}

__device__ inline bf16x8 zero8() {
    bf16x8 r;
#pragma unroll
    for (int j = 0; j < 8; ++j) r[j] = 0;
    return r;
}

// B fragments: cols = output channels, k0..63 = Wf (w[o][3..66]), k64..66 = Wc.
__device__ inline void build_bfrag(const float* __restrict__ w, int col, int half,
                                   bf16x8 bfrag[5][2]) {
#pragma unroll
    for (int c = 0; c < 5; ++c) {
#pragma unroll
        for (int t = 0; t < 2; ++t) {
            const int o = t * 32 + col;
            bf16x8 r;
#pragma unroll
            for (int j = 0; j < 8; ++j) {
                const int k = c * 16 + half * 8 + j;
                float v = 0.f;
                if (k < 64)      v = w[o * CW + 3 + k];
                else if (k < 67) v = w[o * CW + (k - 64)];
                r[j] = f2b(v);
            }
            bfrag[c][t] = r;
        }
    }
}

// Prep: H[r][o] = feat[r]·Wf[o] + sp[r]·Wc[o] for r in [0,NS]; row NS = zeros.
__global__ __launch_bounds__(256, 3) void gc_prep(
    const float* __restrict__ sp,
    const float* __restrict__ feat,
    const float* __restrict__ w,
    unsigned short* __restrict__ Hb)   // [NS+1][64]
{
    const int tid  = threadIdx.x;
    const int lane = tid & 63;
    const int wv   = tid >> 6;
    const int col  = lane & 31;
    const int half = lane >> 5;

    const int tile = blockIdx.x * WAVES + wv;
    if (tile >= PTILES) return;
    const int base = tile * 32;
    const int r    = base + col;

    bf16x8 bfrag[5][2];
    build_bfrag(w, col, half, bfrag);

    bf16x8 A0, A1, A2, A3, a4;
    if (r < NS) {
        const float4* fp = (const float4*)(feat + (size_t)r * CF);
        A0 = pack2(fp[half * 2],      fp[half * 2 + 1]);
        A1 = pack2(fp[4 + half * 2],  fp[4 + half * 2 + 1]);
        A2 = pack2(fp[8 + half * 2],  fp[8 + half * 2 + 1]);
        A3 = pack2(fp[12 + half * 2], fp[12 + half * 2 + 1]);
        a4 = zero8();
        if (half == 0) {
            a4[0] = f2b(sp[r * 3 + 0]);
            a4[1] = f2b(sp[r * 3 + 1]);
            a4[2] = f2b(sp[r * 3 + 2]);
        }
    } else {
        A0 = zero8(); A1 = zero8(); A2 = zero8(); A3 = zero8(); a4 = zero8();
    }

    f32x16 acc0, acc1;
#pragma unroll
    for (int g = 0; g < 16; ++g) { acc0[g] = 0.f; acc1[g] = 0.f; }
    acc0 = __builtin_amdgcn_mfma_f32_32x32x16_bf16(A0, bfrag[0][0], acc0, 0, 0, 0);
    acc1 = __builtin_amdgcn_mfma_f32_32x32x16_bf16(A0, bfrag[0][1], acc1, 0, 0, 0);
    acc0 = __builtin_amdgcn_mfma_f32_32x32x16_bf16(A1, bfrag[1][0], acc0, 0, 0, 0);
    acc1 = __builtin_amdgcn_mfma_f32_32x32x16_bf16(A1, bfrag[1][1], acc1, 0, 0, 0);
    acc0 = __builtin_amdgcn_mfma_f32_32x32x16_bf16(A2, bfrag[2][0], acc0, 0, 0, 0);
    acc1 = __builtin_amdgcn_mfma_f32_32x32x16_bf16(A2, bfrag[2][1], acc1, 0, 0, 0);
    acc0 = __builtin_amdgcn_mfma_f32_32x32x16_bf16(A3, bfrag[3][0], acc0, 0, 0, 0);
    acc1 = __builtin_amdgcn_mfma_f32_32x32x16_bf16(A3, bfrag[3][1], acc1, 0, 0, 0);
    acc0 = __builtin_amdgcn_mfma_f32_32x32x16_bf16(a4, bfrag[4][0], acc0, 0, 0, 0);
    acc1 = __builtin_amdgcn_mfma_f32_32x32x16_bf16(a4, bfrag[4][1], acc1, 0, 0, 0);

    // C layout (verified m74/m101): col = lane&31, row = (g&3)+8*(g>>2)+4*(lane>>5)
#pragma unroll
    for (int g = 0; g < 16; ++g) {
        const int row = (g & 3) + 8 * (g >> 2) + 4 * half;
        const int rr  = base + row;
        if (rr <= NS) {
            Hb[(size_t)rr * CO + col]      = (unsigned short)f2b(acc0[g]);
            Hb[(size_t)rr * CO + 32 + col] = (unsigned short)f2b(acc1[g]);
        }
    }
}

// Gather: wave = 1 query, lane = channel. Per n: readlane (SALU row base) +
// ushort load; epilogue has ZERO validity ops (pad rows are H=0 so sum/sq are
// exact); rare ballot-gated wave-uniform fixup repairs max/min/stats.
template <bool MIN>
__global__ __launch_bounds__(256, 3) void gc_gather(
    const float* __restrict__ qp,
    const unsigned short* __restrict__ Hb,   // [NS+1][64] bf16 bits
    const float* __restrict__ w,
    const int*   __restrict__ inds,
    float* __restrict__ zmax,                // d_out [NQ][64]
    float* __restrict__ zmin,                // ws (optional)
    float* __restrict__ partials)            // [GRIDG][128]
{
    __shared__ float red[WAVES][128];

    const int tid  = threadIdx.x;
    const int lane = tid & 63;
    const int wv   = tid >> 6;

    // per-lane (channel) coordinate weights, register-resident
    const float Wc0 = w[lane * CW + 0];
    const float Wc1 = w[lane * CW + 1];
    const float Wc2 = w[lane * CW + 2];

    float csum = 0.f, csq = 0.f;

    for (int q = blockIdx.x * WAVES + wv; q < NQ; q += GRIDG * WAVES) {
        const int vii = inds[q * KK + (lane & 31)];   // lanes 32-63 duplicate
        const float qx = qp[q * 3 + 0];               // wave-uniform -> s_load
        const float qy = qp[q * 3 + 1];
        const float qz = qp[q * 3 + 2];
        const float qwc = qx * Wc0 + qy * Wc1 + qz * Wc2;

        const unsigned long long pmw = __ballot(vii >= NS);
        const unsigned pm = (unsigned)pmw;            // lo32 == hi32 (dup)

        // issue all 32 row reads (SGPR row base via readlane, voffset = lane*2)
        unsigned int hr[KK];
#pragma unroll
        for (int n = 0; n < KK; ++n) {
            const int iin = __builtin_amdgcn_readlane(vii, n);   // SALU base
            hr[n] = Hb[(size_t)iin * CO + lane];
        }

        float hs = 0.f, hsq = 0.f, hmx = -1e38f, hmn = 1e38f;
#pragma unroll
        for (int n = 0; n < KK; ++n) {
            union { unsigned u; float f; } cv;
            cv.u = hr[n] << 16;                       // bf16 -> f32
            hs += cv.f;                               // pad row H=0: exact
            hsq = fmaf(cv.f, cv.f, hsq);
            hmx = fmaxf(hmx, cv.f);
            if (MIN) hmn = fminf(hmn, cv.f);
        }
        float maxz = hmx - qwc;
        float minz = hmn - qwc;
        csum += fmaf(-32.f, qwc, hs);
        csq  += hsq - 2.f * qwc * hs + 32.f * qwc * qwc;

        if (pm != 0) {   // rare (pad index present): wave-uniform fixup
            const int padc = __popc(pm);
            csum += (float)padc * qwc;                // -32qwc -> -(32-padc)qwc
            csq  -= (float)padc * qwc * qwc;
            hmx = -1e38f; hmn = 1e38f;
#pragma unroll
            for (int n = 0; n < KK; ++n) {
                const bool val = ((pm >> n) & 1u) == 0u;
                union { unsigned u; float f; } cv;
                cv.u = hr[n] << 16;
                hmx = fmaxf(hmx, val ? cv.f : -1e38f);
                if (MIN) hmn = fminf(hmn, val ? cv.f : 1e38f);
            }
            maxz = fmaxf(hmx - qwc, 0.f);             // pad z = 0 exactly
            if (MIN) minz = fminf(hmn - qwc, 0.f);
        }

        zmax[q * CO + lane] = maxz;
        if (MIN) zmin[q * CO + lane] = minz;
    }

    red[wv][lane]      = csum;
    red[wv][64 + lane] = csq;
    __syncthreads();
    if (tid < 128) {
        partials[blockIdx.x * 128 + tid] =
            red[0][tid] + red[1][tid] + red[2][tid] + red[3][tid];
    }
}

// Fallback (ws too small — not expected): R4-style direct gather + MFMA.
__global__ __launch_bounds__(256, 3) void gc_fb(
    const float* __restrict__ qp,
    const float* __restrict__ sp,
    const float* __restrict__ feat,
    const float* __restrict__ w,
    const int*   __restrict__ inds,
    float* __restrict__ zmax,
    float* __restrict__ partials)   // [GRIDFB][128]
{
    __shared__ float red[WAVES][128];
    const int tid  = threadIdx.x;
    const int lane = tid & 63;
    const int wv   = tid >> 6;
    const int col  = lane & 31;
    const int half = lane >> 5;

    bf16x8 bfrag[5][2];
    build_bfrag(w, col, half, bfrag);

    float csum0 = 0.f, csum1 = 0.f, csq0 = 0.f, csq1 = 0.f;

    for (int qb = blockIdx.x * WAVES; qb < NQ; qb += GSFB) {
        const int q = qb + wv;
        const int ii = inds[q * KK + col];
        const bool val = (ii < NS);
        bf16x8 A0, A1, A2, A3, a4;
        if (val) {
            const float4* fp = (const float4*)(feat + (size_t)ii * CF);
            A0 = pack2(fp[half * 2],      fp[half * 2 + 1]);
            A1 = pack2(fp[4 + half * 2],  fp[4 + half * 2 + 1]);
            A2 = pack2(fp[8 + half * 2],  fp[8 + half * 2 + 1]);
            A3 = pack2(fp[12 + half * 2], fp[12 + half * 2 + 1]);
            a4 = zero8();
            if (half == 0) {
                a4[0] = f2b(sp[ii * 3 + 0] - qp[q * 3 + 0]);
                a4[1] = f2b(sp[ii * 3 + 1] - qp[q * 3 + 1]);
                a4[2] = f2b(sp[ii * 3 + 2] - qp[q * 3 + 2]);
            }
        } else {
            A0 = zero8(); A1 = zero8(); A2 = zero8(); A3 = zero8(); a4 = zero8();
        }

        f32x16 acc0, acc1;
#pragma unroll
        for (int g = 0; g < 16; ++g) { acc0[g] = 0.f; acc1[g] = 0.f; }
        acc0 = __builtin_amdgcn_mfma_f32_32x32x16_bf16(A0, bfrag[0][0], acc0, 0, 0, 0);
        acc1 = __builtin_amdgcn_mfma_f32_32x32x16_bf16(A0, bfrag[0][1], acc1, 0, 0, 0);
        acc0 = __builtin_amdgcn_mfma_f32_32x32x16_bf16(A1, bfrag[1][0], acc0, 0, 0, 0);
        acc1 = __builtin_amdgcn_mfma_f32_32x32x16_bf16(A1, bfrag[1][1], acc1, 0, 0, 0);
        acc0 = __builtin_amdgcn_mfma_f32_32x32x16_bf16(A2, bfrag[2][0], acc0, 0, 0, 0);
        acc1 = __builtin_amdgcn_mfma_f32_32x32x16_bf16(A2, bfrag[2][1], acc1, 0, 0, 0);
        acc0 = __builtin_amdgcn_mfma_f32_32x32x16_bf16(A3, bfrag[3][0], acc0, 0, 0, 0);
        acc1 = __builtin_amdgcn_mfma_f32_32x32x16_bf16(A3, bfrag[3][1], acc1, 0, 0, 0);
        acc0 = __builtin_amdgcn_mfma_f32_32x32x16_bf16(a4, bfrag[4][0], acc0, 0, 0, 0);
        acc1 = __builtin_amdgcn_mfma_f32_32x32x16_bf16(a4, bfrag[4][1], acc1, 0, 0, 0);

        float m0 = acc0[0], m1 = acc1[0];
        float s0 = 0.f, s1 = 0.f, q0 = 0.f, q1 = 0.f;
#pragma unroll
        for (int g = 0; g < 16; ++g) {
            m0 = fmaxf(m0, acc0[g]); m1 = fmaxf(m1, acc1[g]);
            s0 += acc0[g]; s1 += acc1[g];
            q0 = fmaf(acc0[g], acc0[g], q0); q1 = fmaf(acc1[g], acc1[g], q1);
        }
        csum0 += s0; csum1 += s1; csq0 += q0; csq1 += q1;
        m0 = fmaxf(m0, __shfl_xor(m0, 32));
        m1 = fmaxf(m1, __shfl_xor(m1, 32));
        zmax[q * CO + half * 32 + col] = half ? m1 : m0;
    }

    csum0 += __shfl_xor(csum0, 32);
    csum1 += __shfl_xor(csum1, 32);
    csq0  += __shfl_xor(csq0, 32);
    csq1  += __shfl_xor(csq1, 32);
    if (lane < 32) {
        red[wv][col]      = csum0;
        red[wv][32 + col] = csum1;
        red[wv][64 + col] = csq0;
        red[wv][96 + col] = csq1;
    }
    __syncthreads();
    if (tid < 128) {
        partials[blockIdx.x * 128 + tid] =
            red[0][tid] + red[1][tid] + red[2][tid] + red[3][tid];
    }
}

// One block per channel: deterministic tree reduction over nblk partials.
__global__ void gc_finalize(const float* __restrict__ partials, int nblk,
                            const float* __restrict__ gamma,
                            const float* __restrict__ beta,
                            float* __restrict__ sb)
{
    __shared__ double rs[256], rq[256];
    const int o = blockIdx.x;
    const int t = threadIdx.x;
    double s = 0.0, qq = 0.0;
    for (int b = t; b < nblk; b += 256) {
        s  += (double)partials[b * 128 + o];
        qq += (double)partials[b * 128 + 64 + o];
    }
    rs[t] = s; rq[t] = qq;
    __syncthreads();
    for (int w2 = 128; w2 > 0; w2 >>= 1) {
        if (t < w2) { rs[t] += rs[t + w2]; rq[t] += rq[t + w2]; }
        __syncthreads();
    }
    if (t == 0) {
        const double n = (double)NQ * (double)KK;
        const double mean = rs[0] / n;
        const double var  = rq[0] / n - mean * mean;
        const float sc = gamma[o] * (float)(1.0 / sqrt(var + 1e-5));
        const float bi = beta[o] - (float)mean * sc;
        sb[o]      = sc;
        sb[64 + o] = bi;
    }
}

// out = leaky(scale * z + bias), in place on d_out (float4-wide).
__global__ void gc_bnact(float4* __restrict__ out,
                         const float4* __restrict__ zmin,
                         const float* __restrict__ sb,
                         int has_min)
{
    const int i  = blockIdx.x * 256 + threadIdx.x;   // < NQ*CO/4
    const int ob = (i & 15) * 4;
    const float4 s4 = *(const float4*)(sb + ob);
    const float4 b4 = *(const float4*)(sb + 64 + ob);
    float4 z4 = out[i];
    if (has_min && (s4.x < 0.f || s4.y < 0.f || s4.z < 0.f || s4.w < 0.f)) {
        const float4 n4 = zmin[i];
        if (s4.x < 0.f) z4.x = n4.x;
        if (s4.y < 0.f) z4.y = n4.y;
        if (s4.z < 0.f) z4.z = n4.z;
        if (s4.w < 0.f) z4.w = n4.w;
    }
    float4 v;
    v.x = s4.x * z4.x + b4.x;
    v.y = s4.y * z4.y + b4.y;
    v.z = s4.z * z4.z + b4.z;
    v.w = s4.w * z4.w + b4.w;
    v.x = (v.x >= 0.f) ? v.x : 0.1f * v.x;
    v.y = (v.y >= 0.f) ? v.y : 0.1f * v.y;
    v.z = (v.z >= 0.f) ? v.z : 0.1f * v.z;
    v.w = (v.w >= 0.f) ? v.w : 0.1f * v.w;
    out[i] = v;
}

extern "C" void kernel_launch(void* const* d_in, const int* in_sizes, int n_in,
                              void* d_out, int out_size, void* d_ws, size_t ws_size,
                              hipStream_t stream) {
    const float* q_points = (const float*)d_in[0];
    const float* s_points = (const float*)d_in[1];
    const float* feat     = (const float*)d_in[2];
    const float* conv_w   = (const float*)d_in[3];
    const float* gamma    = (const float*)d_in[4];
    const float* beta     = (const float*)d_in[5];
    const int*   inds     = (const int*)d_in[6];

    float* ws  = (float*)d_ws;
    float* sb  = ws;                               // 128 floats
    float* par = ws + 128;                         // GRIDG*128 floats
    float* Hf  = par + GRIDG * 128;                // HFULL floats
    float* zmn = Hf + HFULL;                       // NQ*CO floats (optional)

    const size_t need_tab = (size_t)(128 + GRIDG * 128 + HFULL) * 4;   // ~7.45MB
    const size_t need_min = need_tab + (size_t)NQ * CO * 4;            // ~20.2MB
    const bool has_tab = ws_size >= need_tab;
    const bool has_min = ws_size >= need_min;

    float* zmax = (float*)d_out;
    unsigned short* Hb = (unsigned short*)Hf;

    if (has_tab) {
        gc_prep<<<(PTILES + WAVES - 1) / WAVES, 256, 0, stream>>>(
            s_points, feat, conv_w, Hb);
        if (has_min) {
            gc_gather<true><<<GRIDG, 256, 0, stream>>>(
                q_points, Hb, conv_w, inds, zmax, zmn, par);
        } else {
            gc_gather<false><<<GRIDG, 256, 0, stream>>>(
                q_points, Hb, conv_w, inds, zmax, nullptr, par);
        }
        gc_finalize<<<64, 256, 0, stream>>>(par, GRIDG, gamma, beta, sb);
    } else {
        gc_fb<<<GRIDFB, 256, 0, stream>>>(
            q_points, s_points, feat, conv_w, inds, zmax, par);
        gc_finalize<<<64, 256, 0, stream>>>(par, GRIDFB, gamma, beta, sb);
    }
    gc_bnact<<<(NQ * CO / 4 + 255) / 256, 256, 0, stream>>>(
        (float4*)d_out, (const float4*)zmn, sb, (has_min && has_tab) ? 1 : 0);
}